// Round 5
// baseline (224.768 us; speedup 1.0000x reference)
//
#include <hip/hip_runtime.h>
#include <hip/hip_bf16.h>

typedef unsigned short u16;
typedef __attribute__((ext_vector_type(8))) short bf16x8;
typedef __attribute__((ext_vector_type(4))) float f32x4;
typedef __attribute__((ext_vector_type(16))) float f32x16;
typedef __attribute__((ext_vector_type(4))) int i32x4;
typedef __attribute__((ext_vector_type(2))) unsigned int u32x2;

constexpr int SEN  = 128;
constexpr int CIN  = 270;
constexpr int KP   = 384;          // 3 taps * 128 padded channels
constexpr int NOUT = 984;
constexpr int XROW = 256;          // bytes per xT row (16 slots x 16B)
constexpr int XTB  = 130 * XROW;   // 33,280 B per buffer

__device__ inline float ftanh(float x) {
    float e = __expf(2.0f * x);
    return 1.0f - 2.0f * __builtin_amdgcn_rcpf(e + 1.0f);
}
__device__ inline unsigned pk2(float x, float y) {
    union { __hip_bfloat162 h; unsigned u; } v;
    v.h = __float22bfloat162_rn(float2{x, y});
    return v.u;
}

// ---------------------------------------------------------------------------
// prep_all: Av (bf16 weights, K = ktap*128+c), SE3[(e*128+dc)*3+k],
// SR3[((j*40+r)*128+dc)*3+k], plus the independent loc path.
// ---------------------------------------------------------------------------
__global__ void prep_all(const float* __restrict__ w, const float* __restrict__ ee,
                         const float* __restrict__ re, const int* __restrict__ loc,
                         const int* __restrict__ lmark, const float* __restrict__ we,
                         u16* __restrict__ Av, float* __restrict__ SE3,
                         float* __restrict__ SR3, float* __restrict__ out) {
    const int b = blockIdx.x, tid = threadIdx.x;
    if (b < 192) {
        int i = b * 256 + tid;
        int dc = i / KP, K = i - dc * KP;
        int k = K >> 7, c = K & 127;
        float v = (c < 110) ? w[(dc * CIN + c) * 3 + k] : 0.0f;
        union { __hip_bfloat16 h; u16 u; } cv;
        cv.h = __float2bfloat16(v);
        Av[i] = cv.u;
    } else if (b < 252) {
        int i = (b - 192) * 256 + tid;       // < 15360
        int k = i % 3, rest = i / 3;
        int dc = rest & 127, e = rest >> 7;
        float a = 0.f;
        for (int j = 0; j < 32; ++j)
            a += w[(dc * CIN + 110 + j) * 3 + k] * ee[e * 32 + j];
        SE3[i] = a;
    } else if (b < 732) {
        int i = (b - 252) * 256 + tid;       // < 122880
        int k = i % 3, rest = i / 3;
        int dc = rest & 127, rr = rest >> 7;
        int r = rr % 40, j = rr / 40;
        float a = 0.f;
        for (int d = 0; d < 16; ++d)
            a += w[(dc * CIN + 142 + j * 16 + d) * 3 + k] * re[r * 16 + d];
        SR3[i] = a;
    } else {
        int li = b - 732;                    // 0..2047, two samples per block
        int s = li * 2 + (tid >> 7);
        int d = tid & 127;
        if (d < 100) {
            const int* L = loc + (size_t)s * 16;
            float* o = out + (size_t)s * NOUT + 384;
#pragma unroll
            for (int i = 0; i < 4; ++i)
                o[i * 100 + d] = ftanh(we[(size_t)L[i] * 100 + d]);
            int mk = lmark[s];
            float acc = 0.f;
            for (int j = 0; j < mk; ++j)
                acc += we[(size_t)L[4 + j] * 100 + d];
            o[4 * 100 + d] = ftanh(acc / (float)mk);
            o[5 * 100 + d] = ftanh(we[(size_t)L[4 + mk] * 100 + d]);
        }
    }
}

// ---------------------------------------------------------------------------
// Main: 256 blocks x 512 thr. Waves 0-3 = consumers (GEMM 32x32x16 + pool),
// waves 4-7 = producers (gather/convert/stage next sample). 16 samples/block,
// double-buffered LDS, one barrier per sample.
// ---------------------------------------------------------------------------
__global__ __launch_bounds__(512)
__attribute__((amdgpu_waves_per_eu(2, 2)))
void conv_pool(const int* __restrict__ inp, const int* __restrict__ pos1,
               const int* __restrict__ pos2, const int* __restrict__ subtype,
               const int* __restrict__ argRole,
               const float* __restrict__ maskL, const float* __restrict__ maskM,
               const float* __restrict__ maskR,
               const float* __restrict__ we, const float* __restrict__ pe,
               const float* __restrict__ cb,
               const u16* __restrict__ Av, const float* __restrict__ SE3,
               const float* __restrict__ SR3, float* __restrict__ out)
{
    __shared__ __align__(16) char xT[2][XTB];   // 66,560 B
    __shared__ float sc[2][3 * 128];            //  3,072 B

    const int tid  = threadIdx.x;
    const int lane = tid & 63;
    const bool isCons = tid < 256;

    // zero both xT buffers once (pad rows 0/129 and slots 14,15 stay zero)
    {
        i32x4 z = {0, 0, 0, 0};
        i32x4* pz = (i32x4*)xT;
#pragma unroll
        for (int i = 0; i < 9; ++i) {
            int o = tid + i * 512;
            if (o < 2 * XTB / 16) pz[o] = z;
        }
    }
    __syncthreads();

    const int sbase = blockIdx.x * 16;
    const int wq  = tid >> 6;          // consumer: dc slice [wq*32, wq*32+32)
    const int cl31 = lane & 31;
    const int hi   = lane >> 5;

    // ---- consumer: A slice into registers, pinned ----
    i32x4 Af[24];
    if (isCons) {
        const u16* ab = Av + (wq * 32 + cl31) * KP + hi * 8;
#pragma unroll
        for (int ks = 0; ks < 24; ++ks)
            Af[ks] = *(const i32x4*)(ab + ks * 16);
#pragma unroll
        for (int ks = 0; ks < 24; ++ks)
            asm volatile("" : "+v"(Af[ks]));    // forbid rematerialization
    }

    // ---- producer staging ----
    const int p = tid & 255;
    auto stage = [&](int s, char* xb, float* scb) {
        // coalesced word-embedding gather: flat float4 index q over [0,3200)
#pragma unroll
        for (int jj = 0; jj < 13; ++jj) {
            int q = p + jj * 256;
            if (q < 3200) {
                int tok = q / 25;
                int e   = q - tok * 25;
                int idx = inp[s * SEN + tok];
                f32x4 v = *(const f32x4*)(we + (size_t)idx * 100 + e * 4);
                int row  = tok + 1;
                int slot = (e >> 1) ^ (row & 15);
                u32x2 wv = { pk2(v[0], v[1]), pk2(v[2], v[3]) };
                *(u32x2*)(xb + row * XROW + (slot << 4) + (e & 1) * 8) = wv;
            }
        }
        if (p < 128) {
            // const-channel sums for dc = p
            int sub = subtype[s];
            i32x4 a0 = *(const i32x4*)(argRole + s * 8);
            i32x4 a1 = *(const i32x4*)(argRole + s * 8 + 4);
            int arr[8] = {a0[0], a0[1], a0[2], a0[3], a1[0], a1[1], a1[2], a1[3]};
            const float* bb = SE3 + (sub * 128 + p) * 3;
            float sk0 = bb[0], sk1 = bb[1], sk2 = bb[2];
#pragma unroll
            for (int j = 0; j < 8; ++j) {
                const float* rb = SR3 + ((j * 40 + arr[j]) * 128 + p) * 3;
                sk0 += rb[0]; sk1 += rb[1]; sk2 += rb[2];
            }
            scb[p]       = sk0 + sk1 + sk2 + cb[p];
            scb[128 + p] = sk0;
            scb[256 + p] = sk2;
        } else {
            // position embeddings for token t
            int t = p - 128;
            int row = t + 1;
            int p1 = pos1[s * SEN + t], p2 = pos2[s * SEN + t];
            float q0 = pe[p1 * 5],     q1 = pe[p1 * 5 + 1], q2 = pe[p1 * 5 + 2];
            float q3 = pe[p1 * 5 + 3], q4 = pe[p1 * 5 + 4];
            float r0 = pe[p2 * 5],     r1 = pe[p2 * 5 + 1], r2 = pe[p2 * 5 + 2];
            float r3 = pe[p2 * 5 + 3], r4 = pe[p2 * 5 + 4];
            u32x2 wa = { pk2(q0, q1), pk2(q2, q3) };          // c100..103
            *(u32x2*)(xb + row * XROW + ((12 ^ (row & 15)) << 4) + 8) = wa;
            union { bf16x8 v; unsigned u[4]; } wb;             // c104..111
            wb.u[0] = pk2(q4, r0); wb.u[1] = pk2(r1, r2);
            wb.u[2] = pk2(r3, r4); wb.u[3] = 0;
            *(bf16x8*)(xb + row * XROW + ((13 ^ (row & 15)) << 4)) = wb.v;
        }
    };

    // prologue: stage sample 0 into buffer 0
    if (!isCons) stage(sbase, xT[0], sc[0]);
    __syncthreads();

    for (int it = 0; it < 16; ++it) {
        const int s   = sbase + it;
        const int cur = it & 1;

        if (isCons) {
            // masks in flight during GEMM
            float mkv[3][4];
#pragma unroll
            for (int nf = 0; nf < 4; ++nf) {
                size_t mo = (size_t)s * SEN + nf * 32 + cl31;
                mkv[0][nf] = maskL[mo];
                mkv[1][nf] = maskM[mo];
                mkv[2][nf] = maskR[mo];
            }

            f32x16 acc[4];
#pragma unroll
            for (int nf = 0; nf < 4; ++nf)
#pragma unroll
                for (int r = 0; r < 16; ++r) acc[nf][r] = 0.f;

            const char* xc = xT[cur];
#pragma unroll
            for (int ks = 0; ks < 24; ++ks) {
                const int ktap = ks >> 3;
                const int sb   = (ks & 7) * 2 + hi;
                const bf16x8 a = __builtin_bit_cast(bf16x8, Af[ks]);
#pragma unroll
                for (int nf = 0; nf < 4; ++nf) {
                    const int row = nf * 32 + cl31 + ktap;
                    bf16x8 b = *(const bf16x8*)(xc + row * XROW
                                                + ((sb ^ (row & 15)) << 4));
                    acc[nf] = __builtin_amdgcn_mfma_f32_32x32x16_bf16(
                        a, b, acc[nf], 0, 0, 0);
                }
            }

            // ---- epilogue ----
            const float* scc = sc[cur];
            const float e0 = (cl31 == 0)  ? 1.f : 0.f;
            const float e3 = (cl31 == 31) ? 1.f : 0.f;
#pragma unroll
            for (int g = 0; g < 4; ++g) {
                const int base = wq * 32 + 8 * g + 4 * hi;
                f32x4 sav = *(const f32x4*)(scc + base);
                f32x4 s0v = *(const f32x4*)(scc + 128 + base);
                f32x4 s2v = *(const f32x4*)(scc + 256 + base);
#pragma unroll
                for (int rr = 0; rr < 4; ++rr) {
                    const int r = g * 4 + rr;
#pragma unroll
                    for (int nf = 0; nf < 4; ++nf) acc[nf][r] += sav[rr];
                    acc[0][r] -= e0 * s0v[rr];   // token 0 edge
                    acc[3][r] -= e3 * s2v[rr];   // token 127 edge
                }
            }
            float* o = out + (size_t)s * NOUT;
#pragma unroll
            for (int m = 0; m < 3; ++m) {
                float pm[16];
#pragma unroll
                for (int g = 0; g < 4; ++g)
#pragma unroll
                    for (int rr = 0; rr < 4; ++rr) {
                        const int r = g * 4 + rr;
                        float x = __builtin_fmaf(acc[0][r], mkv[m][0], 1.f);
                        x = fmaxf(x, __builtin_fmaf(acc[1][r], mkv[m][1], 1.f));
                        x = fmaxf(x, __builtin_fmaf(acc[2][r], mkv[m][2], 1.f));
                        x = fmaxf(x, __builtin_fmaf(acc[3][r], mkv[m][3], 1.f));
                        pm[r] = x;
                    }
#pragma unroll
                for (int d = 1; d < 32; d <<= 1)
#pragma unroll
                    for (int r = 0; r < 16; ++r)
                        pm[r] = fmaxf(pm[r], __shfl_xor(pm[r], d));
                float v = pm[0];
#pragma unroll
                for (int r = 1; r < 16; ++r)
                    v = (cl31 == r) ? pm[r] : v;
                if (cl31 < 16) {
                    const int x = cl31;
                    const int R = (x & 3) + 8 * (x >> 2) + 4 * hi;
                    o[m * 128 + wq * 32 + R] = ftanh(v - 1.f);
                }
            }
        } else {
            if (it < 15) stage(s + 1, xT[cur ^ 1], sc[cur ^ 1]);
        }
        __syncthreads();
    }
}

// ---------------------------------------------------------------------------
extern "C" void kernel_launch(void* const* d_in, const int* in_sizes, int n_in,
                              void* d_out, int out_size, void* d_ws, size_t ws_size,
                              hipStream_t stream) {
    const int*   inp     = (const int*)d_in[0];
    const int*   pos1    = (const int*)d_in[1];
    const int*   pos2    = (const int*)d_in[2];
    const int*   loc     = (const int*)d_in[3];
    const int*   lmark   = (const int*)d_in[4];
    const int*   subtype = (const int*)d_in[5];
    const int*   argRole = (const int*)d_in[6];
    const float* maskL   = (const float*)d_in[7];
    const float* maskM   = (const float*)d_in[8];
    const float* maskR   = (const float*)d_in[9];
    const float* we      = (const float*)d_in[10];
    const float* pe      = (const float*)d_in[11];
    const float* ee      = (const float*)d_in[12];
    const float* re      = (const float*)d_in[13];
    const float* cw      = (const float*)d_in[14];
    const float* cb      = (const float*)d_in[15];
    float* out = (float*)d_out;

    char* ws = (char*)d_ws;
    u16*   Av  = (u16*)ws;                        // 98,304 B
    float* SE3 = (float*)(ws + 98304);            // 61,440 B
    float* SR3 = (float*)(ws + 98304 + 61440);    // 491,520 B

    hipLaunchKernelGGL(prep_all, dim3(2780), dim3(256), 0, stream,
                       cw, ee, re, loc, lmark, we, Av, SE3, SR3, out);
    hipLaunchKernelGGL(conv_pool, dim3(256), dim3(512), 0, stream,
                       inp, pos1, pos2, subtype, argRole, maskL, maskM, maskR,
                       we, pe, cb, Av, SE3, SR3, out);
}

// Round 7
// 189.771 us; speedup vs baseline: 1.1844x; 1.1844x over previous
//
#include <hip/hip_runtime.h>
#include <hip/hip_bf16.h>

typedef unsigned short u16;
typedef __attribute__((ext_vector_type(8))) short bf16x8;
typedef __attribute__((ext_vector_type(4))) float f32x4;
typedef __attribute__((ext_vector_type(4))) int i32x4;
typedef __attribute__((ext_vector_type(2))) unsigned int u32x2;

constexpr int SEN  = 128;
constexpr int CIN  = 270;
constexpr int KA   = 352;          // A row: 336 real K + 16 zero pad
constexpr int NOUT = 984;
constexpr int XROW = 256;          // bytes per xT row (16 slots x 16B)
constexpr int XTB  = 130 * XROW;   // 33,280 B per buffer

__device__ inline float ftanh(float x) {
    float e = __expf(2.0f * x);
    return 1.0f - 2.0f * __builtin_amdgcn_rcpf(e + 1.0f);
}
__device__ inline unsigned pk2(float x, float y) {
    union { __hip_bfloat162 h; unsigned u; } v;
    v.h = __float22bfloat162_rn(float2{x, y});
    return v.u;
}

// ---------------------------------------------------------------------------
// prep_all: Av[128][352] bf16 (K = tap*112 + ch, ch<110 real), SE3, SR3, loc.
// blocks [0,176): Av  [176,236): SE3  [236,716): SR3  [716,2764): loc
// ---------------------------------------------------------------------------
__global__ void prep_all(const float* __restrict__ w, const float* __restrict__ ee,
                         const float* __restrict__ re, const int* __restrict__ loc,
                         const int* __restrict__ lmark, const float* __restrict__ we,
                         u16* __restrict__ Av, float* __restrict__ SE3,
                         float* __restrict__ SR3, float* __restrict__ out) {
    const int b = blockIdx.x, tid = threadIdx.x;
    if (b < 176) {
        int i = b * 256 + tid;                // < 45056
        int dc = i / KA, K = i - dc * KA;
        int tap = (K >= 112) + (K >= 224) + (K >= 336);
        int ch  = K - 112 * tap;
        float v = (tap < 3 && ch < 110) ? w[(dc * CIN + ch) * 3 + tap] : 0.0f;
        union { __hip_bfloat16 h; u16 u; } cv;
        cv.h = __float2bfloat16(v);
        Av[i] = cv.u;
    } else if (b < 236) {
        int i = (b - 176) * 256 + tid;        // < 15360
        int k = i % 3, rest = i / 3;
        int dc = rest & 127, e = rest >> 7;
        float a = 0.f;
        for (int j = 0; j < 32; ++j)
            a += w[(dc * CIN + 110 + j) * 3 + k] * ee[e * 32 + j];
        SE3[i] = a;
    } else if (b < 716) {
        int i = (b - 236) * 256 + tid;        // < 122880
        int k = i % 3, rest = i / 3;
        int dc = rest & 127, rr = rest >> 7;
        int r = rr % 40, j = rr / 40;
        float a = 0.f;
        for (int d = 0; d < 16; ++d)
            a += w[(dc * CIN + 142 + j * 16 + d) * 3 + k] * re[r * 16 + d];
        SR3[i] = a;
    } else {
        int li = b - 716;                     // 0..2047, two samples per block
        int s = li * 2 + (tid >> 7);
        int d = tid & 127;
        if (d < 100) {
            const int* L = loc + (size_t)s * 16;
            float* o = out + (size_t)s * NOUT + 384;
#pragma unroll
            for (int i = 0; i < 4; ++i)
                o[i * 100 + d] = ftanh(we[(size_t)L[i] * 100 + d]);
            int mk = lmark[s];
            float acc = 0.f;
            for (int j = 0; j < mk; ++j)
                acc += we[(size_t)L[4 + j] * 100 + d];
            o[4 * 100 + d] = ftanh(acc / (float)mk);
            o[5 * 100 + d] = ftanh(we[(size_t)L[4 + mk] * 100 + d]);
        }
    }
}

// ---------------------------------------------------------------------------
// Main: 256 blocks x 512 thr (8 waves). Wave w computes dc [w*16, w*16+16)
// over all 128 tokens (16x16x32, K=336 via 11 chunks). All waves also stage
// the next sample (double-buffered LDS), one barrier per sample.
// ---------------------------------------------------------------------------
__global__ __launch_bounds__(512, 2)
void conv_pool(const int* __restrict__ inp, const int* __restrict__ pos1,
               const int* __restrict__ pos2, const int* __restrict__ subtype,
               const int* __restrict__ argRole,
               const float* __restrict__ maskL, const float* __restrict__ maskM,
               const float* __restrict__ maskR,
               const float* __restrict__ we, const float* __restrict__ pe,
               const float* __restrict__ cb,
               const u16* __restrict__ Av, const float* __restrict__ SE3,
               const float* __restrict__ SR3, float* __restrict__ out)
{
    __shared__ __align__(16) char xT[2][XTB];   // 66,560 B
    __shared__ float sc[2][3 * 128];            //  3,072 B
    __shared__ float msk[2][3 * 128];           //  3,072 B

    const int tid  = threadIdx.x;
    const int lane = tid & 63;
    const int wid  = tid >> 6;        // wave: dc slice [wid*16, wid*16+16)
    const int cl   = lane & 15;
    const int rg   = lane >> 4;

    // zero both xT buffers once (pad rows 0/129 and slots 14,15 stay zero)
    {
        i32x4 z = {0, 0, 0, 0};
        i32x4* pz = (i32x4*)xT;
#pragma unroll
        for (int i = 0; i < 9; ++i) {
            int o = tid + i * 512;
            if (o < 2 * XTB / 16) pz[o] = z;
        }
    }
    __syncthreads();   // zero-fill must complete before any staging writes

    // ---- A slice into registers (44 VGPRs), once per persistent block ----
    i32x4 Af[11];
    {
        const char* ab = (const char*)Av + (wid * 16 + cl) * (KA * 2) + rg * 16;
#pragma unroll
        for (int c = 0; c < 11; ++c)
            Af[c] = *(const i32x4*)(ab + c * 64);
#pragma unroll
        for (int c = 0; c < 11; ++c)
            asm volatile("" : "+v"(Af[c]));    // forbid rematerialization
    }

    // ---- B byte-offsets per chunk (sample-invariant, 11 VGPRs) ----
    // tap clamped to 2: K >= 336 lanes read slots 14/15 (always zero), and
    // row0 stays <= cl+2 so nf=7 reads row <= 129 (in bounds).
    int addrB[11];
#pragma unroll
    for (int c = 0; c < 11; ++c) {
        int g   = 32 * c + 8 * rg;
        int tap = (g >= 112) + (g >= 224);
        int ch  = g - 112 * tap;
        int row0 = cl + tap;
        int phys = (ch >> 3) ^ (row0 & 15);
        addrB[c] = row0 * XROW + (phys << 4);
    }

    const int sbase = blockIdx.x * 16;

    auto stage = [&](int s, char* xb, float* scb, float* mb) {
        // coalesced word-embedding gather: flat float4 index q over [0,3200)
#pragma unroll
        for (int jj = 0; jj < 7; ++jj) {
            int q = tid + jj * 512;
            if (q < 3200) {
                int tok = q / 25;
                int e   = q - tok * 25;
                int idx = inp[s * SEN + tok];
                f32x4 v = *(const f32x4*)(we + (size_t)idx * 100 + e * 4);
                int row  = tok + 1;
                int phys = (e >> 1) ^ (row & 15);
                u32x2 wv = { pk2(v[0], v[1]), pk2(v[2], v[3]) };
                *(u32x2*)(xb + row * XROW + (phys << 4) + (e & 1) * 8) = wv;
            }
        }
        if (tid < 128) {
            // const-channel sums for dc = tid
            int sub = subtype[s];
            i32x4 a0 = *(const i32x4*)(argRole + s * 8);
            i32x4 a1 = *(const i32x4*)(argRole + s * 8 + 4);
            int arr[8] = {a0[0], a0[1], a0[2], a0[3], a1[0], a1[1], a1[2], a1[3]};
            const float* bb = SE3 + (sub * 128 + tid) * 3;
            float sk0 = bb[0], sk1 = bb[1], sk2 = bb[2];
#pragma unroll
            for (int j = 0; j < 8; ++j) {
                const float* rb = SR3 + ((j * 40 + arr[j]) * 128 + tid) * 3;
                sk0 += rb[0]; sk1 += rb[1]; sk2 += rb[2];
            }
            scb[tid]       = sk0 + sk1 + sk2 + cb[tid];
            scb[128 + tid] = sk0;
            scb[256 + tid] = sk2;
        } else if (tid < 256) {
            // position embeddings for token t
            int t = tid - 128;
            int row = t + 1, rx = row & 15;
            int p1 = pos1[s * SEN + t];
            int p2 = pos2[s * SEN + t];
            float q0 = pe[p1 * 5],     q1 = pe[p1 * 5 + 1], q2 = pe[p1 * 5 + 2];
            float q3 = pe[p1 * 5 + 3], q4 = pe[p1 * 5 + 4];
            float r0 = pe[p2 * 5],     r1 = pe[p2 * 5 + 1], r2 = pe[p2 * 5 + 2];
            float r3 = pe[p2 * 5 + 3], r4 = pe[p2 * 5 + 4];
            u32x2 wa = { pk2(q0, q1), pk2(q2, q3) };          // ch 100..103
            *(u32x2*)(xb + row * XROW + ((12 ^ rx) << 4) + 8) = wa;
            union { bf16x8 v; unsigned u[4]; } wb;             // ch 104..111
            wb.u[0] = pk2(q4, r0); wb.u[1] = pk2(r1, r2);
            wb.u[2] = pk2(r3, r4); wb.u[3] = 0;
            *(bf16x8*)(xb + row * XROW + ((13 ^ rx) << 4)) = wb.v;
        } else if (tid < 352) {
            // masks -> LDS, f4-coalesced
            int i = tid - 256;                 // < 96
            int m = i >> 5, j4 = i & 31;
            const float* msrc = (m == 0) ? maskL : (m == 1) ? maskM : maskR;
            *(f32x4*)(mb + m * 128 + j4 * 4) =
                *(const f32x4*)(msrc + (size_t)s * SEN + j4 * 4);
        }
    };

    // prologue: stage sample 0 into buffer 0
    stage(sbase, xT[0], sc[0], msk[0]);
    __syncthreads();

    for (int it = 0; it < 16; ++it) {
        const int s   = sbase + it;
        const int cur = it & 1;
        const char* xc = xT[cur];

        // ---- GEMM: 11 chunks x 8 token-blocks ----
        f32x4 acc[8];
#pragma unroll
        for (int nf = 0; nf < 8; ++nf) acc[nf] = (f32x4){0.f, 0.f, 0.f, 0.f};

#pragma unroll
        for (int c = 0; c < 11; ++c) {
            const bf16x8 a = __builtin_bit_cast(bf16x8, Af[c]);
#pragma unroll
            for (int nf = 0; nf < 8; ++nf) {
                bf16x8 b = *(const bf16x8*)(xc + addrB[c] + nf * 4096);
                acc[nf] = __builtin_amdgcn_mfma_f32_16x16x32_bf16(
                    a, b, acc[nf], 0, 0, 0);
            }
        }

        // ---- epilogue: masked max-pool in registers ----
        const float* scc = sc[cur];
        const float* mc  = msk[cur];
        float sall[4], s0v[4], s2v[4];
#pragma unroll
        for (int r = 0; r < 4; ++r) {
            int dc = wid * 16 + rg * 4 + r;
            sall[r] = scc[dc]; s0v[r] = scc[128 + dc]; s2v[r] = scc[256 + dc];
        }
        float pm[3][4];
#pragma unroll
        for (int m = 0; m < 3; ++m)
#pragma unroll
            for (int r = 0; r < 4; ++r) pm[m][r] = -1e30f;

#pragma unroll
        for (int nf = 0; nf < 8; ++nf) {
            const int tt = nf * 16 + cl;
            const float m0 = mc[tt], m1 = mc[128 + tt], m2 = mc[256 + tt];
#pragma unroll
            for (int r = 0; r < 4; ++r) {
                float v = acc[nf][r] + sall[r];
                if (nf == 0) v -= (cl == 0)  ? s0v[r] : 0.f;   // token 0
                if (nf == 7) v -= (cl == 15) ? s2v[r] : 0.f;   // token 127
                pm[0][r] = fmaxf(pm[0][r], __builtin_fmaf(v, m0, 1.f));
                pm[1][r] = fmaxf(pm[1][r], __builtin_fmaf(v, m1, 1.f));
                pm[2][r] = fmaxf(pm[2][r], __builtin_fmaf(v, m2, 1.f));
            }
        }
#pragma unroll
        for (int m = 0; m < 3; ++m)
#pragma unroll
            for (int r = 0; r < 4; ++r)
#pragma unroll
                for (int d = 1; d < 16; d <<= 1)
                    pm[m][r] = fmaxf(pm[m][r], __shfl_xor(pm[m][r], d));
        if (cl < 3) {
            float* o = out + (size_t)s * NOUT + cl * 128 + wid * 16 + rg * 4;
#pragma unroll
            for (int r = 0; r < 4; ++r) {
                float v = (cl == 0) ? pm[0][r] : (cl == 1) ? pm[1][r] : pm[2][r];
                o[r] = ftanh(v - 1.f);
            }
        }

        // ---- stage next sample into the other buffer ----
        if (it < 15) stage(s + 1, xT[cur ^ 1], sc[cur ^ 1], msk[cur ^ 1]);
        __syncthreads();
    }
}

// ---------------------------------------------------------------------------
extern "C" void kernel_launch(void* const* d_in, const int* in_sizes, int n_in,
                              void* d_out, int out_size, void* d_ws, size_t ws_size,
                              hipStream_t stream) {
    const int*   inp     = (const int*)d_in[0];
    const int*   pos1    = (const int*)d_in[1];
    const int*   pos2    = (const int*)d_in[2];
    const int*   loc     = (const int*)d_in[3];
    const int*   lmark   = (const int*)d_in[4];
    const int*   subtype = (const int*)d_in[5];
    const int*   argRole = (const int*)d_in[6];
    const float* maskL   = (const float*)d_in[7];
    const float* maskM   = (const float*)d_in[8];
    const float* maskR   = (const float*)d_in[9];
    const float* we      = (const float*)d_in[10];
    const float* pe      = (const float*)d_in[11];
    const float* ee      = (const float*)d_in[12];
    const float* re      = (const float*)d_in[13];
    const float* cw      = (const float*)d_in[14];
    const float* cb      = (const float*)d_in[15];
    float* out = (float*)d_out;

    char* ws = (char*)d_ws;
    u16*   Av  = (u16*)ws;                         // 128*352*2 = 90,112 B
    float* SE3 = (float*)(ws + 90112);             // 61,440 B
    float* SR3 = (float*)(ws + 90112 + 61440);     // 491,520 B

    hipLaunchKernelGGL(prep_all, dim3(2764), dim3(256), 0, stream,
                       cw, ee, re, loc, lmark, we, Av, SE3, SR3, out);
    hipLaunchKernelGGL(conv_pool, dim3(256), dim3(512), 0, stream,
                       inp, pos1, pos2, subtype, argRole, maskL, maskM, maskR,
                       we, pe, cb, Av, SE3, SR3, out);
}

// Round 8
// 130.921 us; speedup vs baseline: 1.7168x; 1.4495x over previous
//
#include <hip/hip_runtime.h>
#include <hip/hip_bf16.h>

typedef unsigned short u16;
typedef __attribute__((ext_vector_type(8))) short bf16x8;
typedef __attribute__((ext_vector_type(4))) float f32x4;
typedef __attribute__((ext_vector_type(4))) int i32x4;
typedef __attribute__((ext_vector_type(2))) unsigned int u32x2;

constexpr int SEN  = 128;
constexpr int CIN  = 270;
constexpr int KA   = 352;          // A row: 336 real K + 16 zero pad
constexpr int NOUT = 984;
constexpr int XROW = 256;          // bytes per xT row (16 slots x 16B)
constexpr int XTB  = 130 * XROW;   // 33,280 B per buffer

__device__ inline float ftanh(float x) {
    float e = __expf(2.0f * x);
    return 1.0f - 2.0f * __builtin_amdgcn_rcpf(e + 1.0f);
}
__device__ inline unsigned pk2(float x, float y) {
    union { __hip_bfloat162 h; unsigned u; } v;
    v.h = __float22bfloat162_rn(float2{x, y});
    return v.u;
}

// ---------------------------------------------------------------------------
// prep_all: Av[128][352] bf16 (K = tap*112 + ch, ch<110 real), SE3, SR3, loc.
// blocks [0,176): Av  [176,236): SE3  [236,716): SR3  [716,2764): loc
// ---------------------------------------------------------------------------
__global__ void prep_all(const float* __restrict__ w, const float* __restrict__ ee,
                         const float* __restrict__ re, const int* __restrict__ loc,
                         const int* __restrict__ lmark, const float* __restrict__ we,
                         u16* __restrict__ Av, float* __restrict__ SE3,
                         float* __restrict__ SR3, float* __restrict__ out) {
    const int b = blockIdx.x, tid = threadIdx.x;
    if (b < 176) {
        int i = b * 256 + tid;                // < 45056
        int dc = i / KA, K = i - dc * KA;
        int tap = (K >= 112) + (K >= 224) + (K >= 336);
        int ch  = K - 112 * tap;
        float v = (tap < 3 && ch < 110) ? w[(dc * CIN + ch) * 3 + tap] : 0.0f;
        union { __hip_bfloat16 h; u16 u; } cv;
        cv.h = __float2bfloat16(v);
        Av[i] = cv.u;
    } else if (b < 236) {
        int i = (b - 176) * 256 + tid;        // < 15360
        int k = i % 3, rest = i / 3;
        int dc = rest & 127, e = rest >> 7;
        float a = 0.f;
        for (int j = 0; j < 32; ++j)
            a += w[(dc * CIN + 110 + j) * 3 + k] * ee[e * 32 + j];
        SE3[i] = a;
    } else if (b < 716) {
        int i = (b - 236) * 256 + tid;        // < 122880
        int k = i % 3, rest = i / 3;
        int dc = rest & 127, rr = rest >> 7;
        int r = rr % 40, j = rr / 40;
        float a = 0.f;
        for (int d = 0; d < 16; ++d)
            a += w[(dc * CIN + 142 + j * 16 + d) * 3 + k] * re[r * 16 + d];
        SR3[i] = a;
    } else {
        int li = b - 716;                     // 0..2047, two samples per block
        int s = li * 2 + (tid >> 7);
        int d = tid & 127;
        if (d < 100) {
            const int* L = loc + (size_t)s * 16;
            float* o = out + (size_t)s * NOUT + 384;
#pragma unroll
            for (int i = 0; i < 4; ++i)
                o[i * 100 + d] = ftanh(we[(size_t)L[i] * 100 + d]);
            int mk = lmark[s];
            float acc = 0.f;
            for (int j = 0; j < mk; ++j)
                acc += we[(size_t)L[4 + j] * 100 + d];
            o[4 * 100 + d] = ftanh(acc / (float)mk);
            o[5 * 100 + d] = ftanh(we[(size_t)L[4 + mk] * 100 + d]);
        }
    }
}

// ---------------------------------------------------------------------------
// Main: 512 blocks x 512 thr (8 waves) -> 2 blocks/CU for cross-block TLP.
// Wave w computes dc [w*16, w*16+16) over all 128 tokens (16x16x32, K=336
// via 11 chunks, A register-resident). All waves stage the next sample
// (double-buffered LDS), one barrier per sample, 8 samples per block.
// ---------------------------------------------------------------------------
__global__ __launch_bounds__(512)
__attribute__((amdgpu_waves_per_eu(4)))
void conv_pool(const int* __restrict__ inp, const int* __restrict__ pos1,
               const int* __restrict__ pos2, const int* __restrict__ subtype,
               const int* __restrict__ argRole,
               const float* __restrict__ maskL, const float* __restrict__ maskM,
               const float* __restrict__ maskR,
               const float* __restrict__ we, const float* __restrict__ pe,
               const float* __restrict__ cb,
               const u16* __restrict__ Av, const float* __restrict__ SE3,
               const float* __restrict__ SR3, float* __restrict__ out)
{
    __shared__ __align__(16) char xT[2][XTB];   // 66,560 B
    __shared__ float sc[2][3 * 128];            //  3,072 B
    __shared__ float msk[2][3 * 128];           //  3,072 B

    const int tid  = threadIdx.x;
    const int lane = tid & 63;
    const int wid  = tid >> 6;        // wave: dc slice [wid*16, wid*16+16)
    const int cl   = lane & 15;
    const int rg   = lane >> 4;

    // zero both xT buffers once (pad rows 0/129 and slots 14,15 stay zero)
    {
        i32x4 z = {0, 0, 0, 0};
        i32x4* pz = (i32x4*)xT;
#pragma unroll
        for (int i = 0; i < 9; ++i) {
            int o = tid + i * 512;
            if (o < 2 * XTB / 16) pz[o] = z;
        }
    }
    __syncthreads();   // zero-fill must complete before any staging writes

    // ---- A slice into registers (44 VGPRs), once per persistent block ----
    i32x4 Af[11];
    {
        const char* ab = (const char*)Av + (wid * 16 + cl) * (KA * 2) + rg * 16;
#pragma unroll
        for (int c = 0; c < 11; ++c)
            Af[c] = *(const i32x4*)(ab + c * 64);
#pragma unroll
        for (int c = 0; c < 11; ++c)
            asm volatile("" : "+v"(Af[c]));    // forbid rematerialization
    }

    // ---- B byte-offsets per chunk (sample-invariant, 11 VGPRs) ----
    // tap clamped to 2: K >= 336 lanes read slots 14/15 (always zero), and
    // row0 stays <= cl+2 so nf=7 reads row <= 129 (in bounds).
    int addrB[11];
#pragma unroll
    for (int c = 0; c < 11; ++c) {
        int g   = 32 * c + 8 * rg;
        int tap = (g >= 112) + (g >= 224);
        int ch  = g - 112 * tap;
        int row0 = cl + tap;
        int phys = (ch >> 3) ^ (row0 & 15);
        addrB[c] = row0 * XROW + (phys << 4);
    }

    const int sbase = blockIdx.x * 8;

    auto stage = [&](int s, char* xb, float* scb, float* mb) {
        // coalesced word-embedding gather: flat float4 index q over [0,3200)
#pragma unroll
        for (int jj = 0; jj < 7; ++jj) {
            int q = tid + jj * 512;
            if (q < 3200) {
                int tok = q / 25;
                int e   = q - tok * 25;
                int idx = inp[s * SEN + tok];
                f32x4 v = *(const f32x4*)(we + (size_t)idx * 100 + e * 4);
                int row  = tok + 1;
                int phys = (e >> 1) ^ (row & 15);
                u32x2 wv = { pk2(v[0], v[1]), pk2(v[2], v[3]) };
                *(u32x2*)(xb + row * XROW + (phys << 4) + (e & 1) * 8) = wv;
            }
        }
        if (tid < 128) {
            // const-channel sums for dc = tid
            int sub = subtype[s];
            i32x4 a0 = *(const i32x4*)(argRole + s * 8);
            i32x4 a1 = *(const i32x4*)(argRole + s * 8 + 4);
            int arr[8] = {a0[0], a0[1], a0[2], a0[3], a1[0], a1[1], a1[2], a1[3]};
            const float* bb = SE3 + (sub * 128 + tid) * 3;
            float sk0 = bb[0], sk1 = bb[1], sk2 = bb[2];
#pragma unroll
            for (int j = 0; j < 8; ++j) {
                const float* rb = SR3 + ((j * 40 + arr[j]) * 128 + tid) * 3;
                sk0 += rb[0]; sk1 += rb[1]; sk2 += rb[2];
            }
            scb[tid]       = sk0 + sk1 + sk2 + cb[tid];
            scb[128 + tid] = sk0;
            scb[256 + tid] = sk2;
        } else if (tid < 256) {
            // position embeddings for token t
            int t = tid - 128;
            int row = t + 1, rx = row & 15;
            int p1 = pos1[s * SEN + t];
            int p2 = pos2[s * SEN + t];
            float q0 = pe[p1 * 5],     q1 = pe[p1 * 5 + 1], q2 = pe[p1 * 5 + 2];
            float q3 = pe[p1 * 5 + 3], q4 = pe[p1 * 5 + 4];
            float r0 = pe[p2 * 5],     r1 = pe[p2 * 5 + 1], r2 = pe[p2 * 5 + 2];
            float r3 = pe[p2 * 5 + 3], r4 = pe[p2 * 5 + 4];
            u32x2 wa = { pk2(q0, q1), pk2(q2, q3) };          // ch 100..103
            *(u32x2*)(xb + row * XROW + ((12 ^ rx) << 4) + 8) = wa;
            union { bf16x8 v; unsigned u[4]; } wb;             // ch 104..111
            wb.u[0] = pk2(q4, r0); wb.u[1] = pk2(r1, r2);
            wb.u[2] = pk2(r3, r4); wb.u[3] = 0;
            *(bf16x8*)(xb + row * XROW + ((13 ^ rx) << 4)) = wb.v;
        } else if (tid < 352) {
            // masks -> LDS, f4-coalesced
            int i = tid - 256;                 // < 96
            int m = i >> 5, j4 = i & 31;
            const float* msrc = (m == 0) ? maskL : (m == 1) ? maskM : maskR;
            *(f32x4*)(mb + m * 128 + j4 * 4) =
                *(const f32x4*)(msrc + (size_t)s * SEN + j4 * 4);
        }
    };

    // prologue: stage sample 0 into buffer 0
    stage(sbase, xT[0], sc[0], msk[0]);
    __syncthreads();

    for (int it = 0; it < 8; ++it) {
        const int s   = sbase + it;
        const int cur = it & 1;
        const char* xc = xT[cur];

        // ---- GEMM: 11 chunks x 8 token-blocks ----
        f32x4 acc[8];
#pragma unroll
        for (int nf = 0; nf < 8; ++nf) acc[nf] = (f32x4){0.f, 0.f, 0.f, 0.f};

#pragma unroll
        for (int c = 0; c < 11; ++c) {
            const bf16x8 a = __builtin_bit_cast(bf16x8, Af[c]);
#pragma unroll
            for (int nf = 0; nf < 8; ++nf) {
                bf16x8 b = *(const bf16x8*)(xc + addrB[c] + nf * 4096);
                acc[nf] = __builtin_amdgcn_mfma_f32_16x16x32_bf16(
                    a, b, acc[nf], 0, 0, 0);
            }
        }

        // ---- epilogue: masked max-pool in registers ----
        const float* scc = sc[cur];
        const float* mc  = msk[cur];
        float sall[4], s0v[4], s2v[4];
#pragma unroll
        for (int r = 0; r < 4; ++r) {
            int dc = wid * 16 + rg * 4 + r;
            sall[r] = scc[dc]; s0v[r] = scc[128 + dc]; s2v[r] = scc[256 + dc];
        }
        float pm[3][4];
#pragma unroll
        for (int m = 0; m < 3; ++m)
#pragma unroll
            for (int r = 0; r < 4; ++r) pm[m][r] = -1e30f;

#pragma unroll
        for (int nf = 0; nf < 8; ++nf) {
            const int tt = nf * 16 + cl;
            const float m0 = mc[tt], m1 = mc[128 + tt], m2 = mc[256 + tt];
#pragma unroll
            for (int r = 0; r < 4; ++r) {
                float v = acc[nf][r] + sall[r];
                if (nf == 0) v -= (cl == 0)  ? s0v[r] : 0.f;   // token 0
                if (nf == 7) v -= (cl == 15) ? s2v[r] : 0.f;   // token 127
                pm[0][r] = fmaxf(pm[0][r], __builtin_fmaf(v, m0, 1.f));
                pm[1][r] = fmaxf(pm[1][r], __builtin_fmaf(v, m1, 1.f));
                pm[2][r] = fmaxf(pm[2][r], __builtin_fmaf(v, m2, 1.f));
            }
        }
#pragma unroll
        for (int m = 0; m < 3; ++m)
#pragma unroll
            for (int r = 0; r < 4; ++r)
#pragma unroll
                for (int d = 1; d < 16; d <<= 1)
                    pm[m][r] = fmaxf(pm[m][r], __shfl_xor(pm[m][r], d));
        if (cl < 3) {
            float* o = out + (size_t)s * NOUT + cl * 128 + wid * 16 + rg * 4;
#pragma unroll
            for (int r = 0; r < 4; ++r) {
                float v = (cl == 0) ? pm[0][r] : (cl == 1) ? pm[1][r] : pm[2][r];
                o[r] = ftanh(v - 1.f);
            }
        }

        // ---- stage next sample into the other buffer ----
        if (it < 7) stage(s + 1, xT[cur ^ 1], sc[cur ^ 1], msk[cur ^ 1]);
        __syncthreads();
    }
}

// ---------------------------------------------------------------------------
extern "C" void kernel_launch(void* const* d_in, const int* in_sizes, int n_in,
                              void* d_out, int out_size, void* d_ws, size_t ws_size,
                              hipStream_t stream) {
    const int*   inp     = (const int*)d_in[0];
    const int*   pos1    = (const int*)d_in[1];
    const int*   pos2    = (const int*)d_in[2];
    const int*   loc     = (const int*)d_in[3];
    const int*   lmark   = (const int*)d_in[4];
    const int*   subtype = (const int*)d_in[5];
    const int*   argRole = (const int*)d_in[6];
    const float* maskL   = (const float*)d_in[7];
    const float* maskM   = (const float*)d_in[8];
    const float* maskR   = (const float*)d_in[9];
    const float* we      = (const float*)d_in[10];
    const float* pe      = (const float*)d_in[11];
    const float* ee      = (const float*)d_in[12];
    const float* re      = (const float*)d_in[13];
    const float* cw      = (const float*)d_in[14];
    const float* cb      = (const float*)d_in[15];
    float* out = (float*)d_out;

    char* ws = (char*)d_ws;
    u16*   Av  = (u16*)ws;                         // 128*352*2 = 90,112 B
    float* SE3 = (float*)(ws + 90112);             // 61,440 B
    float* SR3 = (float*)(ws + 90112 + 61440);     // 491,520 B

    hipLaunchKernelGGL(prep_all, dim3(2764), dim3(256), 0, stream,
                       cw, ee, re, loc, lmark, we, Av, SE3, SR3, out);
    hipLaunchKernelGGL(conv_pool, dim3(512), dim3(512), 0, stream,
                       inp, pos1, pos2, subtype, argRole, maskL, maskM, maskR,
                       we, pe, cb, Av, SE3, SR3, out);
}